// Round 8
// baseline (17194.070 us; speedup 1.0000x reference)
//
#include <hip/hip_runtime.h>
#include <stdint.h>
#include <stddef.h>

// TPGRUCell forward, MI355X gfx950.
// R5: combined per-batch recurrent matrices (Az/Ar/Ah) -> per-batch GEMV scan.
// R7: fused tag-publish exchange -> k_scan3 (verified).
// R8/R9: VGPR-residency for A failed twice (allocator remat).  Abandoned.
// R10: gemm128 for phase-1 GEMMs (verified; modest gain -> k_comb dominates).
// R11 (this round):
//  - k_scan3 software-pipelined: A-loads for j=0 issue BEFORE the tag spin
//    (addresses are step-invariant), j-loop rotates load(j+1) || FMA(j).
//    __launch_bounds__(512,4) pins the 4-waves/SIMD VGPR class.
//  - reduction staging transposed to part[24][8][68] ([e][ch][ph]): writes
//    2-way (free), reads contiguous float4 -> kills the 1.0e8 LDS conflicts.
//  - k_comb -> k_comb128 (128x128 tile, s-scale fused in A-staging, W2
//    pre-transposed via k_tr).

#define T_LEN 512
#define BATCH 64
#define DIN   512
#define DH    512
#define DT    128

typedef __attribute__((ext_vector_type(8))) short short8;
typedef __attribute__((ext_vector_type(4))) float f32x4;

static __device__ __forceinline__ float bf2f(unsigned short u) {
  unsigned v = ((unsigned)u) << 16;
  return __builtin_bit_cast(float, v);
}
static __device__ __forceinline__ unsigned short f2bf(float f) {
  unsigned v = __builtin_bit_cast(unsigned, f);
  unsigned r = (v + 0x7fffu + ((v >> 16) & 1u)) >> 16;
  return (unsigned short)r;
}
static __device__ __forceinline__ float sigmoid_f(float x) {
  return 1.f / (1.f + __expf(-x));
}
static __device__ __forceinline__ float tanh_f(float x) {
  float e = __expf(-2.f * fabsf(x));
  float t = (1.f - e) / (1.f + e);
  return copysignf(t, x);
}

// ---------------------------------------------------------------------------
// k_cvt: f32 -> bf16, 8 elems/thread/iter, grid-stride.
// ---------------------------------------------------------------------------
__global__ __launch_bounds__(256) void k_cvt(const float* __restrict__ src,
                                             unsigned short* __restrict__ dst,
                                             int n8) {
  for (int idx = blockIdx.x * 256 + threadIdx.x; idx < n8; idx += gridDim.x * 256) {
    const float4* s = (const float4*)src + 2 * (size_t)idx;
    float4 a = s[0], b = s[1];
    unsigned short d[8];
    d[0] = f2bf(a.x); d[1] = f2bf(a.y); d[2] = f2bf(a.z); d[3] = f2bf(a.w);
    d[4] = f2bf(b.x); d[5] = f2bf(b.y); d[6] = f2bf(b.z); d[7] = f2bf(b.w);
    *(uint4*)(dst + (size_t)idx * 8) = *(const uint4*)d;
  }
}

// ---------------------------------------------------------------------------
// k_tr: dst[n][k] (bf16) = src[k][n] (f32); K,N multiples of 32. LDS-tiled.
// ---------------------------------------------------------------------------
__global__ __launch_bounds__(256) void k_tr(const float* __restrict__ src,
                                            unsigned short* __restrict__ dst,
                                            int K, int N) {
  __shared__ float t[32][33];
  const int tx = threadIdx.x & 31, ty = threadIdx.x >> 5;  // 32 x 8
  const int k0 = blockIdx.y * 32, n0 = blockIdx.x * 32;
  for (int i = ty; i < 32; i += 8)
    t[i][tx] = src[(size_t)(k0 + i) * N + n0 + tx];
  __syncthreads();
  for (int i = ty; i < 32; i += 8)
    dst[(size_t)(n0 + i) * K + k0 + tx] = f2bf(t[tx][i]);
}

// ---------------------------------------------------------------------------
// k_topic: the four topic@W projections, all f32.
// ---------------------------------------------------------------------------
__global__ __launch_bounds__(256) void k_topic(
    const float* __restrict__ topic,
    const float* __restrict__ Wzx,  // [128][1024]
    const float* __restrict__ Wzh,  // [128][1024]
    const float* __restrict__ Whx,  // [128][512]
    const float* __restrict__ Whh,  // [128][512]
    float* __restrict__ tzx, float* __restrict__ tzh,
    float* __restrict__ thx, float* __restrict__ thh)
{
  const int b = blockIdx.x;
  __shared__ float tp[DT];
  if (threadIdx.x < DT) tp[threadIdx.x] = topic[b * DT + threadIdx.x];
  __syncthreads();
  for (int c = threadIdx.x; c < 3072; c += 256) {
    const float* wp; float* op; int ld, cc;
    if (c < 1024)      { wp = Wzx; ld = 1024; cc = c;        op = &tzx[b*1024 + cc]; }
    else if (c < 2048) { wp = Wzh; ld = 1024; cc = c - 1024; op = &tzh[b*1024 + cc]; }
    else if (c < 2560) { wp = Whx; ld = 512;  cc = c - 2048; op = &thx[b*512  + cc]; }
    else               { wp = Whh; ld = 512;  cc = c - 2560; op = &thh[b*512  + cc]; }
    float acc = 0.f;
    #pragma unroll 4
    for (int k = 0; k < DT; ++k) acc += tp[k] * wp[(size_t)k * ld + cc];
    *op = acc;
  }
}

// ---------------------------------------------------------------------------
// gemm128 (phase 1, verified R10): C(bf16) = A(bf16 [M][lda]) @ B with B
// given as BT(bf16 [N][ldb]) = B^T.  128x128 tile, BK=32, 256 thr.
// EPI==0: C *= rs[(row&63)*ldrs+col]; EPI==1: C += bias[col].
// ---------------------------------------------------------------------------
template<int EPI>
__global__ __launch_bounds__(256) void gemm128(
    const unsigned short* __restrict__ A, int lda,
    const unsigned short* __restrict__ BT, int ldb,
    const float* __restrict__ rs, int ldrs,
    const float* __restrict__ bias,
    unsigned short* __restrict__ C, int ldc, int K)
{
  __shared__ unsigned short As[128][48];   // 96B row stride (16B-multiple)
  __shared__ unsigned short Bs[128][48];
  const int tid = threadIdx.x;
  const int n0 = blockIdx.x * 128;
  const int m0 = blockIdx.y * 128;
  const int wv = tid >> 6, lane = tid & 63;
  const int lh = lane & 15, quad = lane >> 4, q8 = quad * 8;
  const int wr = wv >> 1, wc = wv & 1;        // 2x2 wave grid of 64x64
  const int srow = tid >> 1, scol = (tid & 1) * 16;  // staging: row + 16-col half

  f32x4 acc[4][4] = {};

  for (int k0 = 0; k0 < K; k0 += 32) {
    uint4 a4[2], b4[2];
    {
      const unsigned short* ap = A  + (size_t)(m0 + srow) * lda + k0 + scol;
      const unsigned short* bp = BT + (size_t)(n0 + srow) * ldb + k0 + scol;
      a4[0] = ((const uint4*)ap)[0]; a4[1] = ((const uint4*)ap)[1];
      b4[0] = ((const uint4*)bp)[0]; b4[1] = ((const uint4*)bp)[1];
    }
    __syncthreads();   // previous tile fully consumed
    *(uint4*)(&As[srow][scol])     = a4[0];
    *(uint4*)(&As[srow][scol + 8]) = a4[1];
    *(uint4*)(&Bs[srow][scol])     = b4[0];
    *(uint4*)(&Bs[srow][scol + 8]) = b4[1];
    __syncthreads();
    short8 af[4], bf[4];
    #pragma unroll
    for (int i = 0; i < 4; ++i) {
      af[i] = *(const short8*)(&As[wr * 64 + i * 16 + lh][q8]);
      bf[i] = *(const short8*)(&Bs[wc * 64 + i * 16 + lh][q8]);
    }
    #pragma unroll
    for (int i = 0; i < 4; ++i)
      #pragma unroll
      for (int j = 0; j < 4; ++j)
        acc[i][j] = __builtin_amdgcn_mfma_f32_16x16x32_bf16(af[i], bf[j], acc[i][j], 0, 0, 0);
  }

  #pragma unroll
  for (int i = 0; i < 4; ++i)
    #pragma unroll
    for (int j = 0; j < 4; ++j)
      #pragma unroll
      for (int r = 0; r < 4; ++r) {
        int row = m0 + wr * 64 + i * 16 + quad * 4 + r;
        int col = n0 + wc * 64 + j * 16 + lh;
        float v = acc[i][j][r];
        if (EPI == 0) v *= rs[(size_t)(row & 63) * ldrs + col];
        else          v += bias[col];
        C[(size_t)row * ldc + col] = f2bf(v);
      }
}

// ---------------------------------------------------------------------------
// k_comb128: per-batch combined matrix C_b[i][c] = sum_k W1[i][off1+k] *
//   S[b][offS+k] * W2[k][c], with W2 pre-transposed (W2T [n][k] bf16).
// 128x128 tile clone of gemm128; the per-k scale is applied in A-staging
// from an LDS-resident s vector.  Grid (4, 4, 64), 256 thr, K = 512.
// ---------------------------------------------------------------------------
__global__ __launch_bounds__(256) void k_comb128(
    const float* __restrict__ W1, int ld1, int off1,      // [512][ld1] f32
    const unsigned short* __restrict__ W2T,               // [512][512] bf16 [n][k]
    const float* __restrict__ S, int ldS, int offS,       // [64][ldS] f32
    unsigned short* __restrict__ Cout)                    // [64][512][512] bf16
{
  __shared__ unsigned short As[128][48];
  __shared__ unsigned short Bs[128][48];
  __shared__ float sS[512];
  const int tid = threadIdx.x;
  const int n0 = blockIdx.x * 128;
  const int m0 = blockIdx.y * 128;
  const int b  = blockIdx.z;
  const int wv = tid >> 6, lane = tid & 63;
  const int lh = lane & 15, quad = lane >> 4, q8 = quad * 8;
  const int wr = wv >> 1, wc = wv & 1;
  const int srow = tid >> 1, scol = (tid & 1) * 16;

  sS[tid]       = S[(size_t)b * ldS + offS + tid];
  sS[tid + 256] = S[(size_t)b * ldS + offS + tid + 256];
  __syncthreads();

  f32x4 acc[4][4] = {};

  for (int k0 = 0; k0 < 512; k0 += 32) {
    unsigned short a8[16]; uint4 b4[2];
    {
      const float* ap = W1 + (size_t)(m0 + srow) * ld1 + off1 + k0 + scol;
      const unsigned short* bp = W2T + (size_t)(n0 + srow) * 512 + k0 + scol;
      b4[0] = ((const uint4*)bp)[0]; b4[1] = ((const uint4*)bp)[1];
      float4 f0 = ((const float4*)ap)[0], f1 = ((const float4*)ap)[1];
      float4 f2 = ((const float4*)ap)[2], f3 = ((const float4*)ap)[3];
      const float* sp = &sS[k0 + scol];
      a8[0]  = f2bf(f0.x * sp[0]);  a8[1]  = f2bf(f0.y * sp[1]);
      a8[2]  = f2bf(f0.z * sp[2]);  a8[3]  = f2bf(f0.w * sp[3]);
      a8[4]  = f2bf(f1.x * sp[4]);  a8[5]  = f2bf(f1.y * sp[5]);
      a8[6]  = f2bf(f1.z * sp[6]);  a8[7]  = f2bf(f1.w * sp[7]);
      a8[8]  = f2bf(f2.x * sp[8]);  a8[9]  = f2bf(f2.y * sp[9]);
      a8[10] = f2bf(f2.z * sp[10]); a8[11] = f2bf(f2.w * sp[11]);
      a8[12] = f2bf(f3.x * sp[12]); a8[13] = f2bf(f3.y * sp[13]);
      a8[14] = f2bf(f3.z * sp[14]); a8[15] = f2bf(f3.w * sp[15]);
    }
    __syncthreads();
    *(uint4*)(&As[srow][scol])     = *(const uint4*)(a8);
    *(uint4*)(&As[srow][scol + 8]) = *(const uint4*)(a8 + 8);
    *(uint4*)(&Bs[srow][scol])     = b4[0];
    *(uint4*)(&Bs[srow][scol + 8]) = b4[1];
    __syncthreads();
    short8 af[4], bf[4];
    #pragma unroll
    for (int i = 0; i < 4; ++i) {
      af[i] = *(const short8*)(&As[wr * 64 + i * 16 + lh][q8]);
      bf[i] = *(const short8*)(&Bs[wc * 64 + i * 16 + lh][q8]);
    }
    #pragma unroll
    for (int i = 0; i < 4; ++i)
      #pragma unroll
      for (int j = 0; j < 4; ++j)
        acc[i][j] = __builtin_amdgcn_mfma_f32_16x16x32_bf16(af[i], bf[j], acc[i][j], 0, 0, 0);
  }

  #pragma unroll
  for (int i = 0; i < 4; ++i)
    #pragma unroll
    for (int j = 0; j < 4; ++j)
      #pragma unroll
      for (int r = 0; r < 4; ++r) {
        int row = m0 + wr * 64 + i * 16 + quad * 4 + r;
        int col = n0 + wc * 64 + j * 16 + lh;
        Cout[(size_t)b * 262144 + (size_t)row * 512 + col] = f2bf(acc[i][j][r]);
      }
}

static __device__ __forceinline__ void accum8(float* a, float hk, uint4 v) {
  unsigned u0 = v.x, u1 = v.y, u2 = v.z, u3 = v.w;
  a[0] += hk * __builtin_bit_cast(float, u0 << 16);
  a[1] += hk * __builtin_bit_cast(float, u0 & 0xffff0000u);
  a[2] += hk * __builtin_bit_cast(float, u1 << 16);
  a[3] += hk * __builtin_bit_cast(float, u1 & 0xffff0000u);
  a[4] += hk * __builtin_bit_cast(float, u2 << 16);
  a[5] += hk * __builtin_bit_cast(float, u2 & 0xffff0000u);
  a[6] += hk * __builtin_bit_cast(float, u3 << 16);
  a[7] += hk * __builtin_bit_cast(float, u3 & 0xffff0000u);
}

// ---------------------------------------------------------------------------
// k_scan3 (R7 exchange scheme + R11 pipeline/layout):
// Grid = 512 WGs x 512 thr.  WG g: batch b = g>>3, col block w = g&7.
// Exchange: pub[2][64][8][64] u32 regions (32 h-dwords bf16x2 + tag at [32]).
// Producer: data -> vmcnt(0) -> tag = tm+1 (MALL bypass).  Consumer: spin 8
// tags, sync, load.  NEW: j=0 A-loads issue before the spin (step-invariant
// addresses) and the j-loop rotates load(j+1) || FMA(j); part[] transposed
// to [e][ch][ph] stride 68 for conflict-free reduce reads.
// ---------------------------------------------------------------------------
__global__ __launch_bounds__(512, 4) void k_scan3(
    const unsigned short* __restrict__ Az,   // [64][512][512] bf16 (row=k, col=out)
    const unsigned short* __restrict__ Ar,
    const unsigned short* __restrict__ Ah,
    const unsigned short* __restrict__ ZRx,  // [T*64][1024] bf16
    const unsigned short* __restrict__ Hx,   // [T*64][512] bf16
    const float* __restrict__ mask,          // [T*64]
    unsigned* __restrict__ pub,              // [2][64][8][64] u32
    float* out)
{
  const int g = blockIdx.x;
  const int b = g >> 3;
  const int w = g & 7;
  const int c0 = w * 64;
  const int t = threadIdx.x;
  const int chunk = t & 7;
  const int ph = t >> 3;                 // [0,64)
  __shared__ float hs[512];
  __shared__ float part[24][8][68];      // [e][ch][ph], row 272B (16B-aligned)
  __shared__ float red[192];             // [mat*64 + col]

  const size_t mbase = (size_t)b * 262144 + (size_t)ph * 512 + c0 + chunk * 8;
  const unsigned short* pz0 = Az + mbase;
  const unsigned short* pr0 = Ar + mbase;
  const unsigned short* pv0 = Ah + mbase;

  unsigned* pubB0 = pub + (size_t)b * 512;           // parity 0: [8][64]
  unsigned* pubB1 = pub + (size_t)(64 + b) * 512;    // parity 1

  float hold = 0.f;  // master h (f32) for col c0+t, threads t<64
  for (int tm = 0; tm < T_LEN; ++tm) {
    unsigned* pubC = (tm & 1) ? pubB1 : pubB0;   // consume (state after tm steps)
    unsigned* pubP = (tm & 1) ? pubB0 : pubB1;   // produce (state after tm+1)
    const size_t itb = (size_t)tm * BATCH + b;

    // gate-operand prefetch (HBM stream; hides under peer skew/spin)
    float g_zx = 0.f, g_rx = 0.f, g_hx = 0.f, g_m = 0.f;
    if (t < 64) {
      int gc = c0 + t;
      g_zx = bf2f(ZRx[itb * 1024 + gc]);
      g_rx = bf2f(ZRx[itb * 1024 + 512 + gc]);
      g_hx = bf2f(Hx[itb * 512 + gc]);
      g_m  = mask[itb];
    }
    // A-prefetch for j=0: step-invariant addresses, flies during the spin
    uint4 cz = *(const uint4*)(pz0);
    uint4 cr = *(const uint4*)(pr0);
    uint4 cv = *(const uint4*)(pv0);

    // spin: lanes 0..7 poll the 8 region tags of this parity
    if (t < 8) {
      const unsigned* tagp = pubC + t * 64 + 32;
      while ((int)__hip_atomic_load(tagp, __ATOMIC_RELAXED, __HIP_MEMORY_SCOPE_AGENT) < tm)
        ;
    }
    __syncthreads();
    // h data -> LDS (bypass read; bf16x2 -> f32)
    if (t < 256) {
      unsigned v = __hip_atomic_load(pubC + (t >> 5) * 64 + (t & 31),
                                     __ATOMIC_RELAXED, __HIP_MEMORY_SCOPE_AGENT);
      int col = (t >> 5) * 64 + (t & 31) * 2;
      hs[col]     = bf2f((unsigned short)(v & 0xffffu));
      hs[col + 1] = bf2f((unsigned short)(v >> 16));
    }
    __syncthreads();

    // GEMV partials, software-pipelined: load j+1 while FMA j.
    float az[8] = {0,0,0,0,0,0,0,0};
    float ar[8] = {0,0,0,0,0,0,0,0};
    float av[8] = {0,0,0,0,0,0,0,0};
    #pragma unroll
    for (int j = 0; j < 8; ++j) {
      uint4 nz, nr, nv;
      if (j < 7) {
        nz = *(const uint4*)(pz0 + (size_t)(j + 1) * 64 * 512);
        nr = *(const uint4*)(pr0 + (size_t)(j + 1) * 64 * 512);
        nv = *(const uint4*)(pv0 + (size_t)(j + 1) * 64 * 512);
      }
      float hk = hs[ph + 64 * j];
      accum8(az, hk, cz);
      accum8(ar, hk, cr);
      accum8(av, hk, cv);
      if (j < 7) { cz = nz; cr = nr; cv = nv; }
    }
    #pragma unroll
    for (int e = 0; e < 8; ++e) {
      part[e][chunk][ph]      = az[e];
      part[8 + e][chunk][ph]  = ar[e];
      part[16 + e][chunk][ph] = av[e];
    }
    __syncthreads();

    // distributed reduction: 192 threads, contiguous float4 row reads
    if (t < 192) {
      const float* row = &part[t >> 3][t & 7][0];
      float p0 = 0.f, p1 = 0.f, p2 = 0.f, p3 = 0.f;
      #pragma unroll
      for (int q = 0; q < 16; ++q) {
        float4 v = *(const float4*)(row + 4 * q);
        float s = (v.x + v.y) + (v.z + v.w);
        if ((q & 3) == 0) p0 += s;
        else if ((q & 3) == 1) p1 += s;
        else if ((q & 3) == 2) p2 += s;
        else p3 += s;
      }
      int e = t >> 3, ch = t & 7;
      int mat = e >> 3, col = ch * 8 + (e & 7);
      red[mat * 64 + col] = (p0 + p1) + (p2 + p3);
    }
    __syncthreads();

    // gates + publish: wave 0 only (no trailing workgroup barrier)
    if (t < 64) {
      float z  = sigmoid_f(red[t] + g_zx);
      float r  = sigmoid_f(red[64 + t] + g_rx);
      float hv = tanh_f(g_hx + r * red[128 + t]);
      float hnew = (1.f - z) * hv + z * hold;
      hnew = g_m * hnew + (1.f - g_m) * hold;
      hold = hnew;
      int gc = c0 + t;
      out[itb * 512 + gc] = hnew;
      if (tm == T_LEN - 1)
        out[(size_t)T_LEN * BATCH * 512 + (size_t)b * 512 + gc] = hnew;
      // pack 64 bf16 cols into 32 dwords via wave shuffles, publish + tag
      int hb = (int)f2bf(hnew);
      unsigned lo = (unsigned)__shfl(hb, 2 * t);
      unsigned hi = (unsigned)__shfl(hb, 2 * t + 1);
      if (t < 32)
        __hip_atomic_store(pubP + w * 64 + t, lo | (hi << 16),
                           __ATOMIC_RELAXED, __HIP_MEMORY_SCOPE_AGENT);
      asm volatile("s_waitcnt vmcnt(0)" ::: "memory");
      if (t == 0)
        __hip_atomic_store(pubP + w * 64 + 32, (unsigned)(tm + 1),
                           __ATOMIC_RELAXED, __HIP_MEMORY_SCOPE_AGENT);
    }
    // waves 1..7 run ahead; they block at the next spin's __syncthreads,
    // which wave 0 joins only after publishing.
  }
}

// ---------------------------------------------------------------------------
extern "C" void kernel_launch(void* const* d_in, const int* in_sizes, int n_in,
                              void* d_out, int out_size, void* d_ws, size_t ws_size,
                              hipStream_t stream) {
  (void)in_sizes; (void)n_in; (void)out_size; (void)ws_size;
  const float* x        = (const float*)d_in[0];
  const float* topic    = (const float*)d_in[1];
  const float* mask     = (const float*)d_in[2];
  const float* W_x2zr   = (const float*)d_in[3];
  const float* W_tp2zrx = (const float*)d_in[4];
  const float* W_xtp2z  = (const float*)d_in[5];
  const float* b_xtp2z  = (const float*)d_in[6];
  const float* W_xtp2r  = (const float*)d_in[7];
  const float* b_xtp2r  = (const float*)d_in[8];
  const float* W_h2zr   = (const float*)d_in[9];
  const float* W_tp2zrh = (const float*)d_in[10];
  const float* W_htp2z  = (const float*)d_in[11];
  const float* W_htp2r  = (const float*)d_in[12];
  const float* W_x2h    = (const float*)d_in[13];
  const float* W_tp2hx  = (const float*)d_in[14];
  const float* W_xtp2h  = (const float*)d_in[15];
  const float* b_xtp2h  = (const float*)d_in[16];
  const float* W_h2h    = (const float*)d_in[17];
  const float* W_tp2hh  = (const float*)d_in[18];
  const float* W_htp2h  = (const float*)d_in[19];
  float* out = (float*)d_out;

  // ---- workspace carve (~198 MiB) ----
  char* w = (char*)d_ws;
  unsigned* pub = (unsigned*)w;      w += (size_t)2 * 64 * 8 * 64 * 4;  // 256 KB
  float* tzx = (float*)w;           w += (size_t)BATCH * 1024 * 4;
  float* tzh = (float*)w;           w += (size_t)BATCH * 1024 * 4;
  float* thx = (float*)w;           w += (size_t)BATCH * 512 * 4;
  float* thh = (float*)w;           w += (size_t)BATCH * 512 * 4;
  unsigned short* ZRxtp = (unsigned short*)w; w += (size_t)T_LEN * BATCH * 1024 * 2; // 64 MiB
  unsigned short* Hxtp  = (unsigned short*)w; w += (size_t)T_LEN * BATCH * 512 * 2;  // 32 MiB
  unsigned short* SCR   = (unsigned short*)w; w += (size_t)T_LEN * BATCH * 1024 * 2; // 64 MiB
  unsigned short* AhM   = (unsigned short*)w; w += (size_t)BATCH * 512 * 512 * 2;    // 32 MiB
  unsigned short* WzrT  = (unsigned short*)w; w += (size_t)1024 * 512 * 2;           // 1 MiB
  unsigned short* WzT   = (unsigned short*)w; w += (size_t)512 * 512 * 2;
  unsigned short* WrT   = (unsigned short*)w; w += (size_t)512 * 512 * 2;
  unsigned short* WxhT  = (unsigned short*)w; w += (size_t)512 * 512 * 2;
  unsigned short* WhpT  = (unsigned short*)w; w += (size_t)512 * 512 * 2;
  unsigned short* W2zT  = (unsigned short*)w; w += (size_t)512 * 512 * 2;
  unsigned short* W2rT  = (unsigned short*)w; w += (size_t)512 * 512 * 2;
  unsigned short* W2hT  = (unsigned short*)w; w += (size_t)512 * 512 * 2;
  // SCR: phase-1 staging (ZRs, then Xhs), afterwards Az|Ar (2 x 32 MiB).
  // AhM: xb (bf16 x, 32 MiB) during phase 1, then Ah.
  unsigned short* ZRs = SCR;
  unsigned short* Xhs = SCR;
  unsigned short* AzM = SCR;
  unsigned short* ArM = SCR + (size_t)BATCH * 512 * 512;
  unsigned short* xb  = AhM;

  const int M = T_LEN * BATCH;  // 32768

  // pub zeroed: tags = 0 ("0 steps complete"), data = 0 (h0 = 0).
  hipMemsetAsync(pub, 0, (size_t)2 * 64 * 8 * 64 * 4, stream);

  // ---- pre-converts: x -> bf16; weights -> bf16 [n][k] ----
  k_cvt<<<2048, 256, 0, stream>>>(x, xb, (int)((size_t)M * DIN / 8));
  k_tr<<<dim3(1024/32, 512/32), 256, 0, stream>>>(W_x2zr,  WzrT, 512, 1024);
  k_tr<<<dim3( 512/32, 512/32), 256, 0, stream>>>(W_xtp2z, WzT,  512,  512);
  k_tr<<<dim3( 512/32, 512/32), 256, 0, stream>>>(W_xtp2r, WrT,  512,  512);
  k_tr<<<dim3( 512/32, 512/32), 256, 0, stream>>>(W_x2h,   WxhT, 512,  512);
  k_tr<<<dim3( 512/32, 512/32), 256, 0, stream>>>(W_xtp2h, WhpT, 512,  512);
  k_tr<<<dim3( 512/32, 512/32), 256, 0, stream>>>(W_htp2z, W2zT, 512,  512);
  k_tr<<<dim3( 512/32, 512/32), 256, 0, stream>>>(W_htp2r, W2rT, 512,  512);
  k_tr<<<dim3( 512/32, 512/32), 256, 0, stream>>>(W_htp2h, W2hT, 512,  512);

  // ---- phase 1: topic projections + x-side GEMM chain (128x128 tiles) ----
  k_topic<<<BATCH, 256, 0, stream>>>(topic, W_tp2zrx, W_tp2zrh, W_tp2hx, W_tp2hh,
                                     tzx, tzh, thx, thh);
  gemm128<0><<<dim3(1024/128, M/128), 256, 0, stream>>>(
      xb, DIN, WzrT, 512, tzx, 1024, nullptr, ZRs, 1024, DIN);
  gemm128<1><<<dim3(512/128, M/128), 256, 0, stream>>>(
      ZRs, 1024, WzT, 512, nullptr, 0, b_xtp2z, ZRxtp, 1024, 512);
  gemm128<1><<<dim3(512/128, M/128), 256, 0, stream>>>(
      ZRs + 512, 1024, WrT, 512, nullptr, 0, b_xtp2r, ZRxtp + 512, 1024, 512);
  gemm128<0><<<dim3(512/128, M/128), 256, 0, stream>>>(
      xb, DIN, WxhT, 512, thx, 512, nullptr, Xhs, 512, DIN);
  gemm128<1><<<dim3(512/128, M/128), 256, 0, stream>>>(
      Xhs, 512, WhpT, 512, nullptr, 0, b_xtp2h, Hxtp, 512, 512);

  // ---- combined per-batch recurrent matrices (128x128 tiles) ----
  k_comb128<<<dim3(4, 4, 64), 256, 0, stream>>>(W_h2zr, 1024,   0, W2zT, tzh, 1024,   0, AzM);
  k_comb128<<<dim3(4, 4, 64), 256, 0, stream>>>(W_h2zr, 1024, 512, W2rT, tzh, 1024, 512, ArM);
  k_comb128<<<dim3(4, 4, 64), 256, 0, stream>>>(W_h2h,   512,   0, W2hT, thh,  512,   0, AhM);

  // ---- phase 2: per-batch GEMV scan, 64 batches x 8 WGs ----
  k_scan3<<<512, 512, 0, stream>>>(AzM, ArM, AhM, ZRxtp, Hxtp, mask,
                                   pub, out);
}

// Round 9
// 4170.967 us; speedup vs baseline: 4.1223x; 4.1223x over previous
//
#include <hip/hip_runtime.h>
#include <stdint.h>
#include <stddef.h>

// TPGRUCell forward, MI355X gfx950.
// R5: combined per-batch recurrent matrices (Az/Ar/Ah) -> per-batch GEMV scan.
// R7: fused tag-publish exchange -> k_scan3 (verified, 3.12 ms @ VGPR 120).
// R10: gemm128 phase-1 GEMMs.  R11 results: part[] transpose KILLED the LDS
// conflicts (1.0e8 -> 2.6e6, verified) and k_comb128 is fine, but
// __launch_bounds__(512,4) forced VGPR 64 -> scratch spill -> L2 thrash
// (FETCH 27.9 GB, scan 16.1 ms).
// R12 (this round): surgical revert of the launch-bounds pin ONLY.
// Keep: conflict-free part[24][8][68], pipelined j-loop, j=0 prefetch
// before the spin, k_comb128.

#define T_LEN 512
#define BATCH 64
#define DIN   512
#define DH    512
#define DT    128

typedef __attribute__((ext_vector_type(8))) short short8;
typedef __attribute__((ext_vector_type(4))) float f32x4;

static __device__ __forceinline__ float bf2f(unsigned short u) {
  unsigned v = ((unsigned)u) << 16;
  return __builtin_bit_cast(float, v);
}
static __device__ __forceinline__ unsigned short f2bf(float f) {
  unsigned v = __builtin_bit_cast(unsigned, f);
  unsigned r = (v + 0x7fffu + ((v >> 16) & 1u)) >> 16;
  return (unsigned short)r;
}
static __device__ __forceinline__ float sigmoid_f(float x) {
  return 1.f / (1.f + __expf(-x));
}
static __device__ __forceinline__ float tanh_f(float x) {
  float e = __expf(-2.f * fabsf(x));
  float t = (1.f - e) / (1.f + e);
  return copysignf(t, x);
}

// ---------------------------------------------------------------------------
// k_cvt: f32 -> bf16, 8 elems/thread/iter, grid-stride.
// ---------------------------------------------------------------------------
__global__ __launch_bounds__(256) void k_cvt(const float* __restrict__ src,
                                             unsigned short* __restrict__ dst,
                                             int n8) {
  for (int idx = blockIdx.x * 256 + threadIdx.x; idx < n8; idx += gridDim.x * 256) {
    const float4* s = (const float4*)src + 2 * (size_t)idx;
    float4 a = s[0], b = s[1];
    unsigned short d[8];
    d[0] = f2bf(a.x); d[1] = f2bf(a.y); d[2] = f2bf(a.z); d[3] = f2bf(a.w);
    d[4] = f2bf(b.x); d[5] = f2bf(b.y); d[6] = f2bf(b.z); d[7] = f2bf(b.w);
    *(uint4*)(dst + (size_t)idx * 8) = *(const uint4*)d;
  }
}

// ---------------------------------------------------------------------------
// k_tr: dst[n][k] (bf16) = src[k][n] (f32); K,N multiples of 32. LDS-tiled.
// ---------------------------------------------------------------------------
__global__ __launch_bounds__(256) void k_tr(const float* __restrict__ src,
                                            unsigned short* __restrict__ dst,
                                            int K, int N) {
  __shared__ float t[32][33];
  const int tx = threadIdx.x & 31, ty = threadIdx.x >> 5;  // 32 x 8
  const int k0 = blockIdx.y * 32, n0 = blockIdx.x * 32;
  for (int i = ty; i < 32; i += 8)
    t[i][tx] = src[(size_t)(k0 + i) * N + n0 + tx];
  __syncthreads();
  for (int i = ty; i < 32; i += 8)
    dst[(size_t)(n0 + i) * K + k0 + tx] = f2bf(t[tx][i]);
}

// ---------------------------------------------------------------------------
// k_topic: the four topic@W projections, all f32.
// ---------------------------------------------------------------------------
__global__ __launch_bounds__(256) void k_topic(
    const float* __restrict__ topic,
    const float* __restrict__ Wzx,  // [128][1024]
    const float* __restrict__ Wzh,  // [128][1024]
    const float* __restrict__ Whx,  // [128][512]
    const float* __restrict__ Whh,  // [128][512]
    float* __restrict__ tzx, float* __restrict__ tzh,
    float* __restrict__ thx, float* __restrict__ thh)
{
  const int b = blockIdx.x;
  __shared__ float tp[DT];
  if (threadIdx.x < DT) tp[threadIdx.x] = topic[b * DT + threadIdx.x];
  __syncthreads();
  for (int c = threadIdx.x; c < 3072; c += 256) {
    const float* wp; float* op; int ld, cc;
    if (c < 1024)      { wp = Wzx; ld = 1024; cc = c;        op = &tzx[b*1024 + cc]; }
    else if (c < 2048) { wp = Wzh; ld = 1024; cc = c - 1024; op = &tzh[b*1024 + cc]; }
    else if (c < 2560) { wp = Whx; ld = 512;  cc = c - 2048; op = &thx[b*512  + cc]; }
    else               { wp = Whh; ld = 512;  cc = c - 2560; op = &thh[b*512  + cc]; }
    float acc = 0.f;
    #pragma unroll 4
    for (int k = 0; k < DT; ++k) acc += tp[k] * wp[(size_t)k * ld + cc];
    *op = acc;
  }
}

// ---------------------------------------------------------------------------
// gemm128 (phase 1, verified R10): C(bf16) = A(bf16 [M][lda]) @ B with B
// given as BT(bf16 [N][ldb]) = B^T.  128x128 tile, BK=32, 256 thr.
// EPI==0: C *= rs[(row&63)*ldrs+col]; EPI==1: C += bias[col].
// ---------------------------------------------------------------------------
template<int EPI>
__global__ __launch_bounds__(256) void gemm128(
    const unsigned short* __restrict__ A, int lda,
    const unsigned short* __restrict__ BT, int ldb,
    const float* __restrict__ rs, int ldrs,
    const float* __restrict__ bias,
    unsigned short* __restrict__ C, int ldc, int K)
{
  __shared__ unsigned short As[128][48];   // 96B row stride (16B-multiple)
  __shared__ unsigned short Bs[128][48];
  const int tid = threadIdx.x;
  const int n0 = blockIdx.x * 128;
  const int m0 = blockIdx.y * 128;
  const int wv = tid >> 6, lane = tid & 63;
  const int lh = lane & 15, quad = lane >> 4, q8 = quad * 8;
  const int wr = wv >> 1, wc = wv & 1;        // 2x2 wave grid of 64x64
  const int srow = tid >> 1, scol = (tid & 1) * 16;  // staging: row + 16-col half

  f32x4 acc[4][4] = {};

  for (int k0 = 0; k0 < K; k0 += 32) {
    uint4 a4[2], b4[2];
    {
      const unsigned short* ap = A  + (size_t)(m0 + srow) * lda + k0 + scol;
      const unsigned short* bp = BT + (size_t)(n0 + srow) * ldb + k0 + scol;
      a4[0] = ((const uint4*)ap)[0]; a4[1] = ((const uint4*)ap)[1];
      b4[0] = ((const uint4*)bp)[0]; b4[1] = ((const uint4*)bp)[1];
    }
    __syncthreads();   // previous tile fully consumed
    *(uint4*)(&As[srow][scol])     = a4[0];
    *(uint4*)(&As[srow][scol + 8]) = a4[1];
    *(uint4*)(&Bs[srow][scol])     = b4[0];
    *(uint4*)(&Bs[srow][scol + 8]) = b4[1];
    __syncthreads();
    short8 af[4], bf[4];
    #pragma unroll
    for (int i = 0; i < 4; ++i) {
      af[i] = *(const short8*)(&As[wr * 64 + i * 16 + lh][q8]);
      bf[i] = *(const short8*)(&Bs[wc * 64 + i * 16 + lh][q8]);
    }
    #pragma unroll
    for (int i = 0; i < 4; ++i)
      #pragma unroll
      for (int j = 0; j < 4; ++j)
        acc[i][j] = __builtin_amdgcn_mfma_f32_16x16x32_bf16(af[i], bf[j], acc[i][j], 0, 0, 0);
  }

  #pragma unroll
  for (int i = 0; i < 4; ++i)
    #pragma unroll
    for (int j = 0; j < 4; ++j)
      #pragma unroll
      for (int r = 0; r < 4; ++r) {
        int row = m0 + wr * 64 + i * 16 + quad * 4 + r;
        int col = n0 + wc * 64 + j * 16 + lh;
        float v = acc[i][j][r];
        if (EPI == 0) v *= rs[(size_t)(row & 63) * ldrs + col];
        else          v += bias[col];
        C[(size_t)row * ldc + col] = f2bf(v);
      }
}

// ---------------------------------------------------------------------------
// k_comb128: per-batch combined matrix C_b[i][c] = sum_k W1[i][off1+k] *
//   S[b][offS+k] * W2[k][c], with W2 pre-transposed (W2T [n][k] bf16).
// 128x128 tile clone of gemm128; per-k scale applied in A-staging.
// Grid (4, 4, 64), 256 thr, K = 512.  (verified R11)
// ---------------------------------------------------------------------------
__global__ __launch_bounds__(256) void k_comb128(
    const float* __restrict__ W1, int ld1, int off1,      // [512][ld1] f32
    const unsigned short* __restrict__ W2T,               // [512][512] bf16 [n][k]
    const float* __restrict__ S, int ldS, int offS,       // [64][ldS] f32
    unsigned short* __restrict__ Cout)                    // [64][512][512] bf16
{
  __shared__ unsigned short As[128][48];
  __shared__ unsigned short Bs[128][48];
  __shared__ float sS[512];
  const int tid = threadIdx.x;
  const int n0 = blockIdx.x * 128;
  const int m0 = blockIdx.y * 128;
  const int b  = blockIdx.z;
  const int wv = tid >> 6, lane = tid & 63;
  const int lh = lane & 15, quad = lane >> 4, q8 = quad * 8;
  const int wr = wv >> 1, wc = wv & 1;
  const int srow = tid >> 1, scol = (tid & 1) * 16;

  sS[tid]       = S[(size_t)b * ldS + offS + tid];
  sS[tid + 256] = S[(size_t)b * ldS + offS + tid + 256];
  __syncthreads();

  f32x4 acc[4][4] = {};

  for (int k0 = 0; k0 < 512; k0 += 32) {
    unsigned short a8[16]; uint4 b4[2];
    {
      const float* ap = W1 + (size_t)(m0 + srow) * ld1 + off1 + k0 + scol;
      const unsigned short* bp = W2T + (size_t)(n0 + srow) * 512 + k0 + scol;
      b4[0] = ((const uint4*)bp)[0]; b4[1] = ((const uint4*)bp)[1];
      float4 f0 = ((const float4*)ap)[0], f1 = ((const float4*)ap)[1];
      float4 f2 = ((const float4*)ap)[2], f3 = ((const float4*)ap)[3];
      const float* sp = &sS[k0 + scol];
      a8[0]  = f2bf(f0.x * sp[0]);  a8[1]  = f2bf(f0.y * sp[1]);
      a8[2]  = f2bf(f0.z * sp[2]);  a8[3]  = f2bf(f0.w * sp[3]);
      a8[4]  = f2bf(f1.x * sp[4]);  a8[5]  = f2bf(f1.y * sp[5]);
      a8[6]  = f2bf(f1.z * sp[6]);  a8[7]  = f2bf(f1.w * sp[7]);
      a8[8]  = f2bf(f2.x * sp[8]);  a8[9]  = f2bf(f2.y * sp[9]);
      a8[10] = f2bf(f2.z * sp[10]); a8[11] = f2bf(f2.w * sp[11]);
      a8[12] = f2bf(f3.x * sp[12]); a8[13] = f2bf(f3.y * sp[13]);
      a8[14] = f2bf(f3.z * sp[14]); a8[15] = f2bf(f3.w * sp[15]);
    }
    __syncthreads();
    *(uint4*)(&As[srow][scol])     = *(const uint4*)(a8);
    *(uint4*)(&As[srow][scol + 8]) = *(const uint4*)(a8 + 8);
    *(uint4*)(&Bs[srow][scol])     = b4[0];
    *(uint4*)(&Bs[srow][scol + 8]) = b4[1];
    __syncthreads();
    short8 af[4], bf[4];
    #pragma unroll
    for (int i = 0; i < 4; ++i) {
      af[i] = *(const short8*)(&As[wr * 64 + i * 16 + lh][q8]);
      bf[i] = *(const short8*)(&Bs[wc * 64 + i * 16 + lh][q8]);
    }
    #pragma unroll
    for (int i = 0; i < 4; ++i)
      #pragma unroll
      for (int j = 0; j < 4; ++j)
        acc[i][j] = __builtin_amdgcn_mfma_f32_16x16x32_bf16(af[i], bf[j], acc[i][j], 0, 0, 0);
  }

  #pragma unroll
  for (int i = 0; i < 4; ++i)
    #pragma unroll
    for (int j = 0; j < 4; ++j)
      #pragma unroll
      for (int r = 0; r < 4; ++r) {
        int row = m0 + wr * 64 + i * 16 + quad * 4 + r;
        int col = n0 + wc * 64 + j * 16 + lh;
        Cout[(size_t)b * 262144 + (size_t)row * 512 + col] = f2bf(acc[i][j][r]);
      }
}

static __device__ __forceinline__ void accum8(float* a, float hk, uint4 v) {
  unsigned u0 = v.x, u1 = v.y, u2 = v.z, u3 = v.w;
  a[0] += hk * __builtin_bit_cast(float, u0 << 16);
  a[1] += hk * __builtin_bit_cast(float, u0 & 0xffff0000u);
  a[2] += hk * __builtin_bit_cast(float, u1 << 16);
  a[3] += hk * __builtin_bit_cast(float, u1 & 0xffff0000u);
  a[4] += hk * __builtin_bit_cast(float, u2 << 16);
  a[5] += hk * __builtin_bit_cast(float, u2 & 0xffff0000u);
  a[6] += hk * __builtin_bit_cast(float, u3 << 16);
  a[7] += hk * __builtin_bit_cast(float, u3 & 0xffff0000u);
}

// ---------------------------------------------------------------------------
// k_scan3 (R7 exchange + R11 conflict-free layout + pipeline; NO wave pin):
// Grid = 512 WGs x 512 thr.  WG g: batch b = g>>3, col block w = g&7.
// Exchange: pub[2][64][8][64] u32 regions (32 h-dwords bf16x2 + tag at [32]).
// Producer: data -> vmcnt(0) -> tag = tm+1 (MALL bypass).  Consumer: spin 8
// tags, sync, load.  j=0 A-loads issue before the spin; j-loop rotates
// load(j+1) || FMA(j); part[24][8][68] gives conflict-free reduce reads.
// ---------------------------------------------------------------------------
__global__ __launch_bounds__(512) void k_scan3(
    const unsigned short* __restrict__ Az,   // [64][512][512] bf16 (row=k, col=out)
    const unsigned short* __restrict__ Ar,
    const unsigned short* __restrict__ Ah,
    const unsigned short* __restrict__ ZRx,  // [T*64][1024] bf16
    const unsigned short* __restrict__ Hx,   // [T*64][512] bf16
    const float* __restrict__ mask,          // [T*64]
    unsigned* __restrict__ pub,              // [2][64][8][64] u32
    float* out)
{
  const int g = blockIdx.x;
  const int b = g >> 3;
  const int w = g & 7;
  const int c0 = w * 64;
  const int t = threadIdx.x;
  const int chunk = t & 7;
  const int ph = t >> 3;                 // [0,64)
  __shared__ float hs[512];
  __shared__ float part[24][8][68];      // [e][ch][ph], row 272B (16B-aligned)
  __shared__ float red[192];             // [mat*64 + col]

  const size_t mbase = (size_t)b * 262144 + (size_t)ph * 512 + c0 + chunk * 8;
  const unsigned short* pz0 = Az + mbase;
  const unsigned short* pr0 = Ar + mbase;
  const unsigned short* pv0 = Ah + mbase;

  unsigned* pubB0 = pub + (size_t)b * 512;           // parity 0: [8][64]
  unsigned* pubB1 = pub + (size_t)(64 + b) * 512;    // parity 1

  float hold = 0.f;  // master h (f32) for col c0+t, threads t<64
  for (int tm = 0; tm < T_LEN; ++tm) {
    unsigned* pubC = (tm & 1) ? pubB1 : pubB0;   // consume (state after tm steps)
    unsigned* pubP = (tm & 1) ? pubB0 : pubB1;   // produce (state after tm+1)
    const size_t itb = (size_t)tm * BATCH + b;

    // gate-operand prefetch (HBM stream; hides under peer skew/spin)
    float g_zx = 0.f, g_rx = 0.f, g_hx = 0.f, g_m = 0.f;
    if (t < 64) {
      int gc = c0 + t;
      g_zx = bf2f(ZRx[itb * 1024 + gc]);
      g_rx = bf2f(ZRx[itb * 1024 + 512 + gc]);
      g_hx = bf2f(Hx[itb * 512 + gc]);
      g_m  = mask[itb];
    }
    // A-prefetch for j=0: step-invariant addresses, flies during the spin
    uint4 cz = *(const uint4*)(pz0);
    uint4 cr = *(const uint4*)(pr0);
    uint4 cv = *(const uint4*)(pv0);

    // spin: lanes 0..7 poll the 8 region tags of this parity
    if (t < 8) {
      const unsigned* tagp = pubC + t * 64 + 32;
      while ((int)__hip_atomic_load(tagp, __ATOMIC_RELAXED, __HIP_MEMORY_SCOPE_AGENT) < tm)
        ;
    }
    __syncthreads();
    // h data -> LDS (bypass read; bf16x2 -> f32)
    if (t < 256) {
      unsigned v = __hip_atomic_load(pubC + (t >> 5) * 64 + (t & 31),
                                     __ATOMIC_RELAXED, __HIP_MEMORY_SCOPE_AGENT);
      int col = (t >> 5) * 64 + (t & 31) * 2;
      hs[col]     = bf2f((unsigned short)(v & 0xffffu));
      hs[col + 1] = bf2f((unsigned short)(v >> 16));
    }
    __syncthreads();

    // GEMV partials, software-pipelined: load j+1 while FMA j.
    float az[8] = {0,0,0,0,0,0,0,0};
    float ar[8] = {0,0,0,0,0,0,0,0};
    float av[8] = {0,0,0,0,0,0,0,0};
    #pragma unroll
    for (int j = 0; j < 8; ++j) {
      uint4 nz, nr, nv;
      if (j < 7) {
        nz = *(const uint4*)(pz0 + (size_t)(j + 1) * 64 * 512);
        nr = *(const uint4*)(pr0 + (size_t)(j + 1) * 64 * 512);
        nv = *(const uint4*)(pv0 + (size_t)(j + 1) * 64 * 512);
      }
      float hk = hs[ph + 64 * j];
      accum8(az, hk, cz);
      accum8(ar, hk, cr);
      accum8(av, hk, cv);
      if (j < 7) { cz = nz; cr = nr; cv = nv; }
    }
    #pragma unroll
    for (int e = 0; e < 8; ++e) {
      part[e][chunk][ph]      = az[e];
      part[8 + e][chunk][ph]  = ar[e];
      part[16 + e][chunk][ph] = av[e];
    }
    __syncthreads();

    // distributed reduction: 192 threads, contiguous float4 row reads
    if (t < 192) {
      const float* row = &part[t >> 3][t & 7][0];
      float p0 = 0.f, p1 = 0.f, p2 = 0.f, p3 = 0.f;
      #pragma unroll
      for (int q = 0; q < 16; ++q) {
        float4 v = *(const float4*)(row + 4 * q);
        float s = (v.x + v.y) + (v.z + v.w);
        if ((q & 3) == 0) p0 += s;
        else if ((q & 3) == 1) p1 += s;
        else if ((q & 3) == 2) p2 += s;
        else p3 += s;
      }
      int e = t >> 3, ch = t & 7;
      int mat = e >> 3, col = ch * 8 + (e & 7);
      red[mat * 64 + col] = (p0 + p1) + (p2 + p3);
    }
    __syncthreads();

    // gates + publish: wave 0 only (no trailing workgroup barrier)
    if (t < 64) {
      float z  = sigmoid_f(red[t] + g_zx);
      float r  = sigmoid_f(red[64 + t] + g_rx);
      float hv = tanh_f(g_hx + r * red[128 + t]);
      float hnew = (1.f - z) * hv + z * hold;
      hnew = g_m * hnew + (1.f - g_m) * hold;
      hold = hnew;
      int gc = c0 + t;
      out[itb * 512 + gc] = hnew;
      if (tm == T_LEN - 1)
        out[(size_t)T_LEN * BATCH * 512 + (size_t)b * 512 + gc] = hnew;
      // pack 64 bf16 cols into 32 dwords via wave shuffles, publish + tag
      int hb = (int)f2bf(hnew);
      unsigned lo = (unsigned)__shfl(hb, 2 * t);
      unsigned hi = (unsigned)__shfl(hb, 2 * t + 1);
      if (t < 32)
        __hip_atomic_store(pubP + w * 64 + t, lo | (hi << 16),
                           __ATOMIC_RELAXED, __HIP_MEMORY_SCOPE_AGENT);
      asm volatile("s_waitcnt vmcnt(0)" ::: "memory");
      if (t == 0)
        __hip_atomic_store(pubP + w * 64 + 32, (unsigned)(tm + 1),
                           __ATOMIC_RELAXED, __HIP_MEMORY_SCOPE_AGENT);
    }
    // waves 1..7 run ahead; they block at the next spin's __syncthreads,
    // which wave 0 joins only after publishing.
  }
}

// ---------------------------------------------------------------------------
extern "C" void kernel_launch(void* const* d_in, const int* in_sizes, int n_in,
                              void* d_out, int out_size, void* d_ws, size_t ws_size,
                              hipStream_t stream) {
  (void)in_sizes; (void)n_in; (void)out_size; (void)ws_size;
  const float* x        = (const float*)d_in[0];
  const float* topic    = (const float*)d_in[1];
  const float* mask     = (const float*)d_in[2];
  const float* W_x2zr   = (const float*)d_in[3];
  const float* W_tp2zrx = (const float*)d_in[4];
  const float* W_xtp2z  = (const float*)d_in[5];
  const float* b_xtp2z  = (const float*)d_in[6];
  const float* W_xtp2r  = (const float*)d_in[7];
  const float* b_xtp2r  = (const float*)d_in[8];
  const float* W_h2zr   = (const float*)d_in[9];
  const float* W_tp2zrh = (const float*)d_in[10];
  const float* W_htp2z  = (const float*)d_in[11];
  const float* W_htp2r  = (const float*)d_in[12];
  const float* W_x2h    = (const float*)d_in[13];
  const float* W_tp2hx  = (const float*)d_in[14];
  const float* W_xtp2h  = (const float*)d_in[15];
  const float* b_xtp2h  = (const float*)d_in[16];
  const float* W_h2h    = (const float*)d_in[17];
  const float* W_tp2hh  = (const float*)d_in[18];
  const float* W_htp2h  = (const float*)d_in[19];
  float* out = (float*)d_out;

  // ---- workspace carve (~198 MiB) ----
  char* w = (char*)d_ws;
  unsigned* pub = (unsigned*)w;      w += (size_t)2 * 64 * 8 * 64 * 4;  // 256 KB
  float* tzx = (float*)w;           w += (size_t)BATCH * 1024 * 4;
  float* tzh = (float*)w;           w += (size_t)BATCH * 1024 * 4;
  float* thx = (float*)w;           w += (size_t)BATCH * 512 * 4;
  float* thh = (float*)w;           w += (size_t)BATCH * 512 * 4;
  unsigned short* ZRxtp = (unsigned short*)w; w += (size_t)T_LEN * BATCH * 1024 * 2; // 64 MiB
  unsigned short* Hxtp  = (unsigned short*)w; w += (size_t)T_LEN * BATCH * 512 * 2;  // 32 MiB
  unsigned short* SCR   = (unsigned short*)w; w += (size_t)T_LEN * BATCH * 1024 * 2; // 64 MiB
  unsigned short* AhM   = (unsigned short*)w; w += (size_t)BATCH * 512 * 512 * 2;    // 32 MiB
  unsigned short* WzrT  = (unsigned short*)w; w += (size_t)1024 * 512 * 2;           // 1 MiB
  unsigned short* WzT   = (unsigned short*)w; w += (size_t)512 * 512 * 2;
  unsigned short* WrT   = (unsigned short*)w; w += (size_t)512 * 512 * 2;
  unsigned short* WxhT  = (unsigned short*)w; w += (size_t)512 * 512 * 2;
  unsigned short* WhpT  = (unsigned short*)w; w += (size_t)512 * 512 * 2;
  unsigned short* W2zT  = (unsigned short*)w; w += (size_t)512 * 512 * 2;
  unsigned short* W2rT  = (unsigned short*)w; w += (size_t)512 * 512 * 2;
  unsigned short* W2hT  = (unsigned short*)w; w += (size_t)512 * 512 * 2;
  // SCR: phase-1 staging (ZRs, then Xhs), afterwards Az|Ar (2 x 32 MiB).
  // AhM: xb (bf16 x, 32 MiB) during phase 1, then Ah.
  unsigned short* ZRs = SCR;
  unsigned short* Xhs = SCR;
  unsigned short* AzM = SCR;
  unsigned short* ArM = SCR + (size_t)BATCH * 512 * 512;
  unsigned short* xb  = AhM;

  const int M = T_LEN * BATCH;  // 32768

  // pub zeroed: tags = 0 ("0 steps complete"), data = 0 (h0 = 0).
  hipMemsetAsync(pub, 0, (size_t)2 * 64 * 8 * 64 * 4, stream);

  // ---- pre-converts: x -> bf16; weights -> bf16 [n][k] ----
  k_cvt<<<2048, 256, 0, stream>>>(x, xb, (int)((size_t)M * DIN / 8));
  k_tr<<<dim3(1024/32, 512/32), 256, 0, stream>>>(W_x2zr,  WzrT, 512, 1024);
  k_tr<<<dim3( 512/32, 512/32), 256, 0, stream>>>(W_xtp2z, WzT,  512,  512);
  k_tr<<<dim3( 512/32, 512/32), 256, 0, stream>>>(W_xtp2r, WrT,  512,  512);
  k_tr<<<dim3( 512/32, 512/32), 256, 0, stream>>>(W_x2h,   WxhT, 512,  512);
  k_tr<<<dim3( 512/32, 512/32), 256, 0, stream>>>(W_xtp2h, WhpT, 512,  512);
  k_tr<<<dim3( 512/32, 512/32), 256, 0, stream>>>(W_htp2z, W2zT, 512,  512);
  k_tr<<<dim3( 512/32, 512/32), 256, 0, stream>>>(W_htp2r, W2rT, 512,  512);
  k_tr<<<dim3( 512/32, 512/32), 256, 0, stream>>>(W_htp2h, W2hT, 512,  512);

  // ---- phase 1: topic projections + x-side GEMM chain (128x128 tiles) ----
  k_topic<<<BATCH, 256, 0, stream>>>(topic, W_tp2zrx, W_tp2zrh, W_tp2hx, W_tp2hh,
                                     tzx, tzh, thx, thh);
  gemm128<0><<<dim3(1024/128, M/128), 256, 0, stream>>>(
      xb, DIN, WzrT, 512, tzx, 1024, nullptr, ZRs, 1024, DIN);
  gemm128<1><<<dim3(512/128, M/128), 256, 0, stream>>>(
      ZRs, 1024, WzT, 512, nullptr, 0, b_xtp2z, ZRxtp, 1024, 512);
  gemm128<1><<<dim3(512/128, M/128), 256, 0, stream>>>(
      ZRs + 512, 1024, WrT, 512, nullptr, 0, b_xtp2r, ZRxtp + 512, 1024, 512);
  gemm128<0><<<dim3(512/128, M/128), 256, 0, stream>>>(
      xb, DIN, WxhT, 512, thx, 512, nullptr, Xhs, 512, DIN);
  gemm128<1><<<dim3(512/128, M/128), 256, 0, stream>>>(
      Xhs, 512, WhpT, 512, nullptr, 0, b_xtp2h, Hxtp, 512, 512);

  // ---- combined per-batch recurrent matrices (128x128 tiles) ----
  k_comb128<<<dim3(4, 4, 64), 256, 0, stream>>>(W_h2zr, 1024,   0, W2zT, tzh, 1024,   0, AzM);
  k_comb128<<<dim3(4, 4, 64), 256, 0, stream>>>(W_h2zr, 1024, 512, W2rT, tzh, 1024, 512, ArM);
  k_comb128<<<dim3(4, 4, 64), 256, 0, stream>>>(W_h2h,   512,   0, W2hT, thh,  512,   0, AhM);

  // ---- phase 2: per-batch GEMV scan, 64 batches x 8 WGs ----
  k_scan3<<<512, 512, 0, stream>>>(AzM, ArM, AhM, ZRxtp, Hxtp, mask,
                                   pub, out);
}